// Round 1
// baseline (86.994 us; speedup 1.0000x reference)
//
#include <hip/hip_runtime.h>

#define Nn 8
#define Cc 4
#define Hh 256
#define Ww 256

// Workspace layout (bytes):
//   g2T    : [n][j][k] float4 (4 classes packed)  -> 8*256*256*16 = 8,388,608
//   tT     : [n][j][k] uchar                      ->   524,288
//   probsT : [n][j][i] float4 (4 classes packed)  -> 8,388,608
//   partials: [2048] float                        ->     8,192
#define OFF_G2T     0
#define OFF_TT      8388608
#define OFF_PROBST  8912896
#define OFF_PART    17301504

// ---------------------------------------------------------------------------
// Kernel A: per-row 1-D distance to nearest pixel of each class (capped 512),
// squared, written transposed as [n][j][k][c]; also transposed target bytes.
// One thread per image row; 64 rows (one wave) per block.
// ---------------------------------------------------------------------------
__global__ __launch_bounds__(64) void edt_rows_kernel(
    const int* __restrict__ tgt, float4* __restrict__ g2T,
    unsigned char* __restrict__ tT) {
  __shared__ unsigned char s_t[64][260];  // +4 pad -> conflict-free
  const int tid = threadIdx.x;
  const int rowBase = blockIdx.x * 64;  // global row = n*256 + k

  // cooperative coalesced load of 64 rows x 256 ints, packed to bytes
  for (int r = 0; r < 64; ++r) {
    const int4 v = reinterpret_cast<const int4*>(tgt + (rowBase + r) * Ww)[tid];
    uchar4 b;
    b.x = (unsigned char)v.x; b.y = (unsigned char)v.y;
    b.z = (unsigned char)v.z; b.w = (unsigned char)v.w;
    *reinterpret_cast<uchar4*>(&s_t[r][tid * 4]) = b;
  }
  __syncthreads();

  const int n = rowBase >> 8;
  const int k = (rowBase & 255) + tid;           // row index within sample
  const int colBase = n * (Hh * Ww);             // float4 units

  // forward: distance to nearest class-c pixel at or left of j
  int l0 = -512, l1 = -512, l2 = -512, l3 = -512;
  for (int j = 0; j < Ww; ++j) {
    const int t = s_t[tid][j];
    l0 = (t == 0) ? j : l0;
    l1 = (t == 1) ? j : l1;
    l2 = (t == 2) ? j : l2;
    l3 = (t == 3) ? j : l3;
    float4 f;
    f.x = (float)(j - l0);
    f.y = (float)(j - l1);
    f.z = (float)(j - l2);
    f.w = (float)(j - l3);
    g2T[colBase + j * Hh + k] = f;   // coalesced: lanes have consecutive k
  }
  // backward: min with right distance, cap at 512 (=H+W as in reference), square
  int r0 = 9999, r1 = 9999, r2 = 9999, r3 = 9999;
  for (int j = Ww - 1; j >= 0; --j) {
    const int t = s_t[tid][j];
    r0 = (t == 0) ? j : r0;
    r1 = (t == 1) ? j : r1;
    r2 = (t == 2) ? j : r2;
    r3 = (t == 3) ? j : r3;
    float4 f = g2T[colBase + j * Hh + k];
    const int g0 = min(min((int)f.x, r0 - j), 512);
    const int g1 = min(min((int)f.y, r1 - j), 512);
    const int g2 = min(min((int)f.z, r2 - j), 512);
    const int g3 = min(min((int)f.w, r3 - j), 512);
    f.x = (float)(g0 * g0);
    f.y = (float)(g1 * g1);
    f.z = (float)(g2 * g2);
    f.w = (float)(g3 * g3);
    g2T[colBase + j * Hh + k] = f;
    tT[colBase + j * Hh + k] = (unsigned char)t;
  }
}

// ---------------------------------------------------------------------------
// Kernel T: per-pixel softmax over C, written transposed [n][j][i][c] (float4)
// ---------------------------------------------------------------------------
__global__ __launch_bounds__(256) void softmaxT_kernel(
    const float* __restrict__ in, float4* __restrict__ probsT) {
  __shared__ float s[Cc][32][66];  // stride 66 -> <=4-way, cheap
  const int bid = blockIdx.x;      // 8 n * 8 i-tiles * 4 j-tiles = 256
  const int n = bid >> 5;
  const int it = (bid >> 2) & 7;
  const int jt = bid & 3;
  const int i0 = it * 32, j0 = jt * 64;
  const int tid = threadIdx.x;
  {
    const int dj = tid & 63, dr = tid >> 6;
    for (int c = 0; c < Cc; ++c) {
      const float* p = in + ((n * Cc + c) * Hh) * Ww;
      for (int r = dr; r < 32; r += 4)
        s[c][r][dj] = p[(i0 + r) * Ww + j0 + dj];  // coalesced along j
    }
  }
  __syncthreads();
  const int di = tid & 31, grp = tid >> 5;
  for (int q = 0; q < 8; ++q) {
    const int jj = grp * 8 + q;
    const float x0 = s[0][di][jj], x1 = s[1][di][jj];
    const float x2 = s[2][di][jj], x3 = s[3][di][jj];
    const float m = fmaxf(fmaxf(x0, x1), fmaxf(x2, x3));
    const float e0 = expf(x0 - m), e1 = expf(x1 - m);
    const float e2 = expf(x2 - m), e3 = expf(x3 - m);
    const float rs = 1.0f / (e0 + e1 + e2 + e3);
    float4 o;
    o.x = e0 * rs; o.y = e1 * rs; o.z = e2 * rs; o.w = e3 * rs;
    probsT[n * (Hh * Ww) + (j0 + jj) * Hh + (i0 + di)] = o;  // coalesced along i
  }
}

// ---------------------------------------------------------------------------
// Kernel B: per column (n,j): d2_c(i) = min_k g2_c(k) + (i-k)^2 via 17-tap
// window with exact wave-uniform full-scan fallback; fused loss + reduction.
// ---------------------------------------------------------------------------
__global__ __launch_bounds__(256) void edt_cols_kernel(
    const float4* __restrict__ g2T, const unsigned char* __restrict__ tT,
    const float4* __restrict__ probsT, float* __restrict__ partials) {
  __shared__ float4 s_g2[Hh];
  __shared__ float s_w[4];
  const int bid = blockIdx.x;   // n*256 + j
  const int tid = threadIdx.x;  // i
  s_g2[tid] = g2T[bid * Hh + tid];
  __syncthreads();

  const int i = tid;
  float d0 = 3.4e38f, d1 = 3.4e38f, d2 = 3.4e38f, d3 = 3.4e38f;
#pragma unroll
  for (int o = -8; o <= 8; ++o) {
    int k = i + o;
    k = (k < 0) ? 0 : ((k > Hh - 1) ? (Hh - 1) : k);
    // clamped duplicates only ever overestimate -> never break the min
    const float dd = (float)(o * o);
    const float4 gk = s_g2[k];
    d0 = fminf(d0, gk.x + dd);
    d1 = fminf(d1, gk.y + dd);
    d2 = fminf(d2, gk.z + dd);
    d3 = fminf(d3, gk.w + dd);
  }
  // Exactness: any k outside |i-k|<=8 contributes >= 81. If all mins <= 81,
  // the window result is the true min. Otherwise rescan everything (rare).
  const float worst = fmaxf(fmaxf(d0, d1), fmaxf(d2, d3));
  if (__any(worst > 81.0f)) {
    for (int kk = 0; kk < Hh; ++kk) {
      const float d = (float)(i - kk);
      const float dd = d * d;
      const float4 gk = s_g2[kk];
      d0 = fminf(d0, gk.x + dd);
      d1 = fminf(d1, gk.y + dd);
      d2 = fminf(d2, gk.z + dd);
      d3 = fminf(d3, gk.w + dd);
    }
  }

  const int t = tT[bid * Hh + i];
  const float4 p = probsT[bid * Hh + i];
  // dbar = min over classes != t (own-class d is exactly 0)
  const float e0 = (t == 0) ? 3.4e38f : d0;
  const float e1 = (t == 1) ? 3.4e38f : d1;
  const float e2 = (t == 2) ? 3.4e38f : d2;
  const float e3 = (t == 3) ? 3.4e38f : d3;
  const float dbar = fminf(fminf(e0, e1), fminf(e2, e3));
  const float pt = (t == 0) ? p.x : (t == 1) ? p.y : (t == 2) ? p.z : p.w;
  // sum_c p_c * sdt_c ; sqrt(d_t)=0 so the subtraction is safe to include
  float contrib = pt * sqrtf(dbar) -
                  (p.x * sqrtf(d0) + p.y * sqrtf(d1) +
                   p.z * sqrtf(d2) + p.w * sqrtf(d3));

  // block reduction (deterministic fixed order)
#pragma unroll
  for (int off = 32; off > 0; off >>= 1) contrib += __shfl_down(contrib, off);
  if ((tid & 63) == 0) s_w[tid >> 6] = contrib;
  __syncthreads();
  if (tid == 0) partials[bid] = (s_w[0] + s_w[1]) + (s_w[2] + s_w[3]);
}

// ---------------------------------------------------------------------------
// Kernel C: deterministic final reduction + scaling
// ---------------------------------------------------------------------------
__global__ __launch_bounds__(256) void finalize_kernel(
    const float* __restrict__ partials, float* __restrict__ out) {
  __shared__ float s[256];
  float a = 0.0f;
  for (int idx = threadIdx.x; idx < Nn * Ww; idx += 256) a += partials[idx];
  s[threadIdx.x] = a;
  __syncthreads();
  for (int st = 128; st > 0; st >>= 1) {
    if (threadIdx.x < st) s[threadIdx.x] += s[threadIdx.x + st];
    __syncthreads();
  }
  if (threadIdx.x == 0)
    out[0] = s[0] / (float)(Cc * Nn) / (65536.0f + 1e-6f);
}

extern "C" void kernel_launch(void* const* d_in, const int* in_sizes, int n_in,
                              void* d_out, int out_size, void* d_ws, size_t ws_size,
                              hipStream_t stream) {
  const float* input = (const float*)d_in[0];   // [8,4,256,256] fp32 logits
  const int* target = (const int*)d_in[1];      // [8,256,256] int32
  float* out = (float*)d_out;                   // scalar fp32
  char* ws = (char*)d_ws;
  float4* g2T = (float4*)(ws + OFF_G2T);
  unsigned char* tT = (unsigned char*)(ws + OFF_TT);
  float4* probsT = (float4*)(ws + OFF_PROBST);
  float* partials = (float*)(ws + OFF_PART);

  softmaxT_kernel<<<dim3(256), dim3(256), 0, stream>>>(input, probsT);
  edt_rows_kernel<<<dim3((Nn * Hh) / 64), dim3(64), 0, stream>>>(target, g2T, tT);
  edt_cols_kernel<<<dim3(Nn * Ww), dim3(256), 0, stream>>>(g2T, tT, probsT, partials);
  finalize_kernel<<<dim3(1), dim3(256), 0, stream>>>(partials, out);
}

// Round 2
// 51.293 us; speedup vs baseline: 1.6960x; 1.6960x over previous
//
#include <hip/hip_runtime.h>

#define Nn 8
#define Cc 4
#define Hh 256
#define Ww 256

// Workspace layout (bytes):
//   g2T    : [n][j][k] float4 (4 classes packed)  -> 8*256*256*16 = 8,388,608
//   tT     : [n][j][k] uchar                      ->   524,288
//   probsT : [n][j][i] float4 (4 classes packed)  -> 8,388,608
//   partials: [2048] float                        ->     8,192
#define OFF_G2T     0
#define OFF_TT      8388608
#define OFF_PROBST  8912896
#define OFF_PART    17301504

// ---------------------------------------------------------------------------
// Kernel A (parallelized): per-pixel windowed (+-16) row-distance per class,
// exact full-row LDS fallback when a class is missing from the window
// (P ~ 3e-4/pixel). Block = 4 rows x 256 cols. Thread (kk=tid&3, jb=tid>>2)
// handles j = jb + 64*m  ->  transposed writes are aligned 64B chunks.
// Row stride 304 (=76 words, 76%32=12) -> tap reads bank-conflict-free.
// ---------------------------------------------------------------------------
__global__ __launch_bounds__(256) void edt_rows_kernel(
    const int* __restrict__ tgt, float4* __restrict__ g2T,
    unsigned char* __restrict__ tT) {
  __shared__ unsigned char s_t[4][304];  // [kk][16 + j]; pads hold 255 sentinel
  const int tid = threadIdx.x;
  const int rowBase = blockIdx.x * 4;    // global row = n*256 + k
  const int n = rowBase >> 8;
  const int k0 = rowBase & 255;

  // sentinel pads: j-index range touched is [-16, 271] -> bytes [0..287]
  if (tid < 128) {
    const int r = tid >> 5, c = tid & 31;
    s_t[r][(c < 16) ? c : (272 + c - 16)] = 255;
  }
  // cooperative coalesced load: 4 rows x 64 int4, one per thread, pack to bytes
  {
    const int r = tid >> 6, q = tid & 63;
    const int4 v = reinterpret_cast<const int4*>(tgt + (rowBase + r) * Ww)[q];
    uchar4 b;
    b.x = (unsigned char)v.x; b.y = (unsigned char)v.y;
    b.z = (unsigned char)v.z; b.w = (unsigned char)v.w;
    *reinterpret_cast<uchar4*>(&s_t[r][16 + q * 4]) = b;
  }
  __syncthreads();

  const int kk = tid & 3;
  const int jb = tid >> 2;
  const int outBase = n * (Hh * Ww) + k0 + kk;  // float4 / byte units

  for (int m = 0; m < 4; ++m) {
    const int j = jb + (m << 6);
    const unsigned char* row = &s_t[kk][16 + j];
    int d0 = 512, d1 = 512, d2 = 512, d3 = 512;
#pragma unroll
    for (int o = -16; o <= 16; ++o) {
      const int t = row[o];
      const int ad = (o < 0) ? -o : o;  // compile-time constant per tap
      d0 = min(d0, (t == 0) ? ad : 512);
      d1 = min(d1, (t == 1) ? ad : 512);
      d2 = min(d2, (t == 2) ? ad : 512);
      d3 = min(d3, (t == 3) ? ad : 512);
    }
    // exact rare fallback: some class absent in +-16 window -> rescan full row
    if (max(max(d0, d1), max(d2, d3)) > 16) {
      for (int jj = 0; jj < Ww; ++jj) {
        const int t = s_t[kk][16 + jj];
        const int ad = (j >= jj) ? (j - jj) : (jj - j);
        d0 = min(d0, (t == 0) ? ad : 512);
        d1 = min(d1, (t == 1) ? ad : 512);
        d2 = min(d2, (t == 2) ? ad : 512);
        d3 = min(d3, (t == 3) ? ad : 512);
      }
    }
    float4 f;
    f.x = (float)(d0 * d0);
    f.y = (float)(d1 * d1);
    f.z = (float)(d2 * d2);
    f.w = (float)(d3 * d3);
    g2T[outBase + j * Hh] = f;                    // 64B-aligned 4-lane chunks
    tT[outBase + j * Hh] = (unsigned char)row[0];
  }
}

// ---------------------------------------------------------------------------
// Kernel T: per-pixel softmax over C, written transposed [n][j][i][c] (float4)
// ---------------------------------------------------------------------------
__global__ __launch_bounds__(256) void softmaxT_kernel(
    const float* __restrict__ in, float4* __restrict__ probsT) {
  __shared__ float s[Cc][32][66];
  const int bid = blockIdx.x;      // 8 n * 8 i-tiles * 4 j-tiles = 256
  const int n = bid >> 5;
  const int it = (bid >> 2) & 7;
  const int jt = bid & 3;
  const int i0 = it * 32, j0 = jt * 64;
  const int tid = threadIdx.x;
  {
    const int dj = tid & 63, dr = tid >> 6;
    for (int c = 0; c < Cc; ++c) {
      const float* p = in + ((n * Cc + c) * Hh) * Ww;
      for (int r = dr; r < 32; r += 4)
        s[c][r][dj] = p[(i0 + r) * Ww + j0 + dj];  // coalesced along j
    }
  }
  __syncthreads();
  const int di = tid & 31, grp = tid >> 5;
  for (int q = 0; q < 8; ++q) {
    const int jj = grp * 8 + q;
    const float x0 = s[0][di][jj], x1 = s[1][di][jj];
    const float x2 = s[2][di][jj], x3 = s[3][di][jj];
    const float m = fmaxf(fmaxf(x0, x1), fmaxf(x2, x3));
    const float e0 = expf(x0 - m), e1 = expf(x1 - m);
    const float e2 = expf(x2 - m), e3 = expf(x3 - m);
    const float rs = 1.0f / (e0 + e1 + e2 + e3);
    float4 o;
    o.x = e0 * rs; o.y = e1 * rs; o.z = e2 * rs; o.w = e3 * rs;
    probsT[n * (Hh * Ww) + (j0 + jj) * Hh + (i0 + di)] = o;  // coalesced along i
  }
}

// ---------------------------------------------------------------------------
// Kernel B: per column (n,j): d2_c(i) = min_k g2_c(k) + (i-k)^2 via 17-tap
// window with exact wave-uniform full-scan fallback; fused loss + reduction.
// ---------------------------------------------------------------------------
__global__ __launch_bounds__(256) void edt_cols_kernel(
    const float4* __restrict__ g2T, const unsigned char* __restrict__ tT,
    const float4* __restrict__ probsT, float* __restrict__ partials) {
  __shared__ float4 s_g2[Hh];
  __shared__ float s_w[4];
  const int bid = blockIdx.x;   // n*256 + j
  const int tid = threadIdx.x;  // i
  s_g2[tid] = g2T[bid * Hh + tid];
  __syncthreads();

  const int i = tid;
  float d0 = 3.4e38f, d1 = 3.4e38f, d2 = 3.4e38f, d3 = 3.4e38f;
#pragma unroll
  for (int o = -8; o <= 8; ++o) {
    int k = i + o;
    k = (k < 0) ? 0 : ((k > Hh - 1) ? (Hh - 1) : k);
    // clamped duplicates only ever overestimate -> never break the min
    const float dd = (float)(o * o);
    const float4 gk = s_g2[k];
    d0 = fminf(d0, gk.x + dd);
    d1 = fminf(d1, gk.y + dd);
    d2 = fminf(d2, gk.z + dd);
    d3 = fminf(d3, gk.w + dd);
  }
  // Exactness: any k outside |i-k|<=8 contributes >= 81. If all mins <= 81,
  // the window result is the true min. Otherwise rescan everything (rare).
  const float worst = fmaxf(fmaxf(d0, d1), fmaxf(d2, d3));
  if (__any(worst > 81.0f)) {
    for (int kk = 0; kk < Hh; ++kk) {
      const float d = (float)(i - kk);
      const float dd = d * d;
      const float4 gk = s_g2[kk];
      d0 = fminf(d0, gk.x + dd);
      d1 = fminf(d1, gk.y + dd);
      d2 = fminf(d2, gk.z + dd);
      d3 = fminf(d3, gk.w + dd);
    }
  }

  const int t = tT[bid * Hh + i];
  const float4 p = probsT[bid * Hh + i];
  // dbar = min over classes != t (own-class d is exactly 0)
  const float e0 = (t == 0) ? 3.4e38f : d0;
  const float e1 = (t == 1) ? 3.4e38f : d1;
  const float e2 = (t == 2) ? 3.4e38f : d2;
  const float e3 = (t == 3) ? 3.4e38f : d3;
  const float dbar = fminf(fminf(e0, e1), fminf(e2, e3));
  const float pt = (t == 0) ? p.x : (t == 1) ? p.y : (t == 2) ? p.z : p.w;
  // sum_c p_c * sdt_c ; sqrt(d_t)=0 so the subtraction is safe to include
  float contrib = pt * sqrtf(dbar) -
                  (p.x * sqrtf(d0) + p.y * sqrtf(d1) +
                   p.z * sqrtf(d2) + p.w * sqrtf(d3));

  // block reduction (deterministic fixed order)
#pragma unroll
  for (int off = 32; off > 0; off >>= 1) contrib += __shfl_down(contrib, off);
  if ((tid & 63) == 0) s_w[tid >> 6] = contrib;
  __syncthreads();
  if (tid == 0) partials[bid] = (s_w[0] + s_w[1]) + (s_w[2] + s_w[3]);
}

// ---------------------------------------------------------------------------
// Kernel C: deterministic final reduction + scaling
// ---------------------------------------------------------------------------
__global__ __launch_bounds__(256) void finalize_kernel(
    const float* __restrict__ partials, float* __restrict__ out) {
  __shared__ float s[256];
  float a = 0.0f;
  for (int idx = threadIdx.x; idx < Nn * Ww; idx += 256) a += partials[idx];
  s[threadIdx.x] = a;
  __syncthreads();
  for (int st = 128; st > 0; st >>= 1) {
    if (threadIdx.x < st) s[threadIdx.x] += s[threadIdx.x + st];
    __syncthreads();
  }
  if (threadIdx.x == 0)
    out[0] = s[0] / (float)(Cc * Nn) / (65536.0f + 1e-6f);
}

extern "C" void kernel_launch(void* const* d_in, const int* in_sizes, int n_in,
                              void* d_out, int out_size, void* d_ws, size_t ws_size,
                              hipStream_t stream) {
  const float* input = (const float*)d_in[0];   // [8,4,256,256] fp32 logits
  const int* target = (const int*)d_in[1];      // [8,256,256] int32
  float* out = (float*)d_out;                   // scalar fp32
  char* ws = (char*)d_ws;
  float4* g2T = (float4*)(ws + OFF_G2T);
  unsigned char* tT = (unsigned char*)(ws + OFF_TT);
  float4* probsT = (float4*)(ws + OFF_PROBST);
  float* partials = (float*)(ws + OFF_PART);

  softmaxT_kernel<<<dim3(256), dim3(256), 0, stream>>>(input, probsT);
  edt_rows_kernel<<<dim3((Nn * Hh) / 4), dim3(256), 0, stream>>>(target, g2T, tT);
  edt_cols_kernel<<<dim3(Nn * Ww), dim3(256), 0, stream>>>(g2T, tT, probsT, partials);
  finalize_kernel<<<dim3(1), dim3(256), 0, stream>>>(partials, out);
}

// Round 3
// 25.878 us; speedup vs baseline: 3.3617x; 1.9821x over previous
//
#include <hip/hip_runtime.h>

#define Nn 8
#define Cc 4
#define Hh 256
#define Ww 256

// Workspace layout (bytes):
//   gT     : [n][j][k] ushort4 (per-class row distance g, <=512) -> 4,194,304
//   probsT : [n][j][i] float4                                    -> 8,388,608
//   partials: [2048] float                                       ->     8,192
#define OFF_GT      0
#define OFF_PROBST  4194304
#define OFF_PART    12582912

// ---------------------------------------------------------------------------
// Kernel A: exact per-row 1-D nearest-class distance via 256-bit class masks.
// Block = 8 rows x 256 cols (1024 thr). Phase 1: one __ballot per (wave,class)
// builds the masks. Phase 2: per pixel, 64-bit window funnel-shift + clz/ctz
// gives the exact distance when the class appears within [-32,+31]; otherwise
// a rare exact 4-word scan (cap 512 = reference BIG). g written as ushort4 in
// [n][j][k] layout; lanes 0-7 = consecutive k -> full 64B line writes.
// ---------------------------------------------------------------------------
__global__ __launch_bounds__(1024) void edt_rows_kernel(
    const int* __restrict__ tgt, ushort4* __restrict__ gT) {
  // [row][class][guard0, w0..w3, guard, pad] ; stride 7 -> <=2-way LDS (free)
  __shared__ unsigned long long smp[8][4][7];
  const int tid = threadIdx.x;
  const int lane = tid & 63;
  const int n = blockIdx.x >> 5;          // 32 blocks per sample
  const int k0 = (blockIdx.x & 31) * 8;

  if (tid < 64) {  // zero the guard words (idx 0 and 5)
    smp[tid >> 3][(tid >> 1) & 3][(tid & 1) * 5] = 0ull;
  }
  {
    const int r = tid >> 7;               // row 0..7
    const int h = (tid >> 6) & 1;         // 64-bit word half
    const int j1 = h * 64 + lane;
    const int rowOff = (n * Hh + k0 + r) * Ww;
    const int t1 = tgt[rowOff + j1];
    const int t2 = tgt[rowOff + j1 + 128];
#pragma unroll
    for (int c = 0; c < Cc; ++c) {
      const unsigned long long m1 = __ballot(t1 == c);
      const unsigned long long m2 = __ballot(t2 == c);
      if (lane == 0) {
        smp[r][c][1 + h] = m1;
        smp[r][c][3 + h] = m2;
      }
    }
  }
  __syncthreads();

  const int kk = tid & 7;
  const int jb = tid >> 3;                // 0..127
  const int outB = n * (Hh * Ww) + k0 + kk;  // ushort4 units
#pragma unroll
  for (int half = 0; half < 2; ++half) {
    const int j = jb + half * 128;
    const int S = j + 32;                 // padded bitspace: orig bit x = 64+x
    const int word = S >> 6;              // 0..4 (0 and beyond-4+1 hit guards)
    const int sh = S & 63;
    int d[4];
#pragma unroll
    for (int c = 0; c < Cc; ++c) {
      const unsigned long long* M = smp[kk][c];
      const unsigned long long lo = M[word];
      const unsigned long long hi = M[word + 1];
      const unsigned long long win =
          sh ? ((lo >> sh) | (hi << (64 - sh))) : lo;  // bits [j-32, j+31]
      const unsigned long long ml = win & 0x1FFFFFFFFull;  // <= pixel (bit 32)
      const unsigned long long mr = win >> 32;             // >= pixel
      int dd;
      if (ml | mr) {
        const int dl = ml ? (__builtin_clzll(ml) - 31) : 512;
        const int dr = mr ? (int)__builtin_ctzll(mr) : 512;
        dd = min(dl, dr);
      } else {
        // exact rare fallback: full 4-word scan both directions
        int dl = 512, dr = 512;
#pragma unroll
        for (int w = 3; w >= 0; --w) {
          if (w * 64 <= j) {
            unsigned long long m = M[1 + w];
            if (w == (j >> 6)) {
              const int r6 = j & 63;
              m &= (r6 == 63) ? ~0ull : ((1ull << (r6 + 1)) - 1ull);
            }
            if (m && dl == 512) dl = j - (w * 64 + 63 - __builtin_clzll(m));
          }
        }
#pragma unroll
        for (int w = 0; w < 4; ++w) {
          if (w * 64 + 63 >= j) {
            unsigned long long m = M[1 + w];
            if (w == (j >> 6)) m &= ~((1ull << (j & 63)) - 1ull);
            if (m && dr == 512) dr = w * 64 + (int)__builtin_ctzll(m) - j;
          }
        }
        dd = min(min(dl, dr), 512);
      }
      d[c] = dd;
    }
    ushort4 out;
    out.x = (unsigned short)d[0];
    out.y = (unsigned short)d[1];
    out.z = (unsigned short)d[2];
    out.w = (unsigned short)d[3];
    gT[outB + j * Hh] = out;              // 8 lanes -> 64B contiguous
  }
}

// ---------------------------------------------------------------------------
// Kernel T: per-pixel softmax over C, written transposed [n][j][i][c] (float4)
// ---------------------------------------------------------------------------
__global__ __launch_bounds__(256) void softmaxT_kernel(
    const float* __restrict__ in, float4* __restrict__ probsT) {
  __shared__ float s[Cc][32][66];
  const int bid = blockIdx.x;      // 8 n * 8 i-tiles * 4 j-tiles = 256
  const int n = bid >> 5;
  const int it = (bid >> 2) & 7;
  const int jt = bid & 3;
  const int i0 = it * 32, j0 = jt * 64;
  const int tid = threadIdx.x;
  {
    const int dj = tid & 63, dr = tid >> 6;
    for (int c = 0; c < Cc; ++c) {
      const float* p = in + ((n * Cc + c) * Hh) * Ww;
      for (int r = dr; r < 32; r += 4)
        s[c][r][dj] = p[(i0 + r) * Ww + j0 + dj];  // coalesced along j
    }
  }
  __syncthreads();
  const int di = tid & 31, grp = tid >> 5;
  for (int q = 0; q < 8; ++q) {
    const int jj = grp * 8 + q;
    const float x0 = s[0][di][jj], x1 = s[1][di][jj];
    const float x2 = s[2][di][jj], x3 = s[3][di][jj];
    const float m = fmaxf(fmaxf(x0, x1), fmaxf(x2, x3));
    const float e0 = expf(x0 - m), e1 = expf(x1 - m);
    const float e2 = expf(x2 - m), e3 = expf(x3 - m);
    const float rs = 1.0f / (e0 + e1 + e2 + e3);
    float4 o;
    o.x = e0 * rs; o.y = e1 * rs; o.z = e2 * rs; o.w = e3 * rs;
    probsT[n * (Hh * Ww) + (j0 + jj) * Hh + (i0 + di)] = o;  // coalesced along i
  }
}

// ---------------------------------------------------------------------------
// Kernel B: per column (n,j): d2_c(i) = min_k g_c(k)^2 + (i-k)^2 via 17-tap
// window with exact wave-uniform full-scan fallback; fused loss + reduction.
// Pixel class derived as the unique c with d2_c == 0 (tT eliminated).
// ---------------------------------------------------------------------------
__global__ __launch_bounds__(256) void edt_cols_kernel(
    const ushort4* __restrict__ gT, const float4* __restrict__ probsT,
    float* __restrict__ partials) {
  __shared__ float4 s_g2[Hh];
  __shared__ float s_w[4];
  const int bid = blockIdx.x;   // n*256 + j
  const int tid = threadIdx.x;  // i
  {
    const ushort4 gv = gT[bid * Hh + tid];
    float4 f;
    f.x = (float)((int)gv.x * (int)gv.x);
    f.y = (float)((int)gv.y * (int)gv.y);
    f.z = (float)((int)gv.z * (int)gv.z);
    f.w = (float)((int)gv.w * (int)gv.w);
    s_g2[tid] = f;
  }
  __syncthreads();

  const int i = tid;
  float d0 = 3.4e38f, d1 = 3.4e38f, d2 = 3.4e38f, d3 = 3.4e38f;
#pragma unroll
  for (int o = -8; o <= 8; ++o) {
    int k = i + o;
    k = (k < 0) ? 0 : ((k > Hh - 1) ? (Hh - 1) : k);
    // clamped duplicates only ever overestimate -> never break the min
    const float dd = (float)(o * o);
    const float4 gk = s_g2[k];
    d0 = fminf(d0, gk.x + dd);
    d1 = fminf(d1, gk.y + dd);
    d2 = fminf(d2, gk.z + dd);
    d3 = fminf(d3, gk.w + dd);
  }
  // Exactness: any k outside |i-k|<=8 contributes >= 81. If all mins <= 81,
  // the window result is the true min. Otherwise rescan everything (rare).
  const float worst = fmaxf(fmaxf(d0, d1), fmaxf(d2, d3));
  if (__any(worst > 81.0f)) {
    for (int kk = 0; kk < Hh; ++kk) {
      const float d = (float)(i - kk);
      const float dd = d * d;
      const float4 gk = s_g2[kk];
      d0 = fminf(d0, gk.x + dd);
      d1 = fminf(d1, gk.y + dd);
      d2 = fminf(d2, gk.z + dd);
      d3 = fminf(d3, gk.w + dd);
    }
  }

  const float4 p = probsT[bid * Hh + i];
  // own-class d is exactly 0 (g=0 at o=0); exclude it for dbar
  const float e0 = (d0 == 0.0f) ? 3.4e38f : d0;
  const float e1 = (d1 == 0.0f) ? 3.4e38f : d1;
  const float e2 = (d2 == 0.0f) ? 3.4e38f : d2;
  const float e3 = (d3 == 0.0f) ? 3.4e38f : d3;
  const float dbar = fminf(fminf(e0, e1), fminf(e2, e3));
  const float pt = (d0 == 0.0f) ? p.x
                 : (d1 == 0.0f) ? p.y
                 : (d2 == 0.0f) ? p.z : p.w;
  // sum_c p_c * sdt_c ; sqrt of own-class d is 0 so including it is safe
  float contrib = pt * sqrtf(dbar) -
                  (p.x * sqrtf(d0) + p.y * sqrtf(d1) +
                   p.z * sqrtf(d2) + p.w * sqrtf(d3));

  // block reduction (deterministic fixed order)
#pragma unroll
  for (int off = 32; off > 0; off >>= 1) contrib += __shfl_down(contrib, off);
  if ((tid & 63) == 0) s_w[tid >> 6] = contrib;
  __syncthreads();
  if (tid == 0) partials[bid] = (s_w[0] + s_w[1]) + (s_w[2] + s_w[3]);
}

// ---------------------------------------------------------------------------
// Kernel C: deterministic final reduction + scaling
// ---------------------------------------------------------------------------
__global__ __launch_bounds__(256) void finalize_kernel(
    const float* __restrict__ partials, float* __restrict__ out) {
  __shared__ float s[256];
  float a = 0.0f;
  for (int idx = threadIdx.x; idx < Nn * Ww; idx += 256) a += partials[idx];
  s[threadIdx.x] = a;
  __syncthreads();
  for (int st = 128; st > 0; st >>= 1) {
    if (threadIdx.x < st) s[threadIdx.x] += s[threadIdx.x + st];
    __syncthreads();
  }
  if (threadIdx.x == 0)
    out[0] = s[0] / (float)(Cc * Nn) / (65536.0f + 1e-6f);
}

extern "C" void kernel_launch(void* const* d_in, const int* in_sizes, int n_in,
                              void* d_out, int out_size, void* d_ws, size_t ws_size,
                              hipStream_t stream) {
  const float* input = (const float*)d_in[0];   // [8,4,256,256] fp32 logits
  const int* target = (const int*)d_in[1];      // [8,256,256] int32
  float* out = (float*)d_out;                   // scalar fp32
  char* ws = (char*)d_ws;
  ushort4* gT = (ushort4*)(ws + OFF_GT);
  float4* probsT = (float4*)(ws + OFF_PROBST);
  float* partials = (float*)(ws + OFF_PART);

  edt_rows_kernel<<<dim3((Nn * Hh) / 8), dim3(1024), 0, stream>>>(target, gT);
  softmaxT_kernel<<<dim3(256), dim3(256), 0, stream>>>(input, probsT);
  edt_cols_kernel<<<dim3(Nn * Ww), dim3(256), 0, stream>>>(gT, probsT, partials);
  finalize_kernel<<<dim3(1), dim3(256), 0, stream>>>(partials, out);
}

// Round 4
// 22.709 us; speedup vs baseline: 3.8307x; 1.1395x over previous
//
#include <hip/hip_runtime.h>

#define Nn 8
#define Cc 4
#define Hh 256
#define Ww 256

// Workspace layout (bytes):
//   g       : [n][k][j] ushort4 (per-class row distance, <=512) -> 4,194,304
//   partials: [256] float                                       ->     1,024
//   counter : 1 uint (ticket for last-block reduction)
#define OFF_G    0
#define OFF_PART 4194304
#define OFF_CNT  4195328

// ---------------------------------------------------------------------------
// Kernel A: exact per-row 1-D nearest-class distance via 256-bit class masks.
// Block = 8 rows x 256 cols (1024 thr). Phase 1: one __ballot per (wave,class)
// builds the masks. Phase 2: 64-bit window funnel-shift + clz/ctz gives the
// exact distance when the class appears within [-32,+31]; rare exact 4-word
// scan otherwise (cap 512 = reference BIG). Natural [n][k][j] writes, lanes =
// consecutive j -> perfectly coalesced. Also zeroes the ticket counter.
// ---------------------------------------------------------------------------
__global__ __launch_bounds__(1024) void edt_rows_kernel(
    const int* __restrict__ tgt, ushort4* __restrict__ g,
    unsigned* __restrict__ counter) {
  // [row][class][guard0, w0..w3, guard5, pad] ; stride 7 -> <=2-way (free)
  __shared__ unsigned long long smp[8][4][7];
  const int tid = threadIdx.x;
  const int lane = tid & 63;
  const int n = blockIdx.x >> 5;          // 32 blocks per sample
  const int k0 = (blockIdx.x & 31) * 8;

  if (blockIdx.x == 0 && tid == 0) *counter = 0u;  // visible to next kernel
  if (tid < 64) {  // zero the guard words (idx 0 and 5)
    smp[tid >> 3][(tid >> 1) & 3][(tid & 1) * 5] = 0ull;
  }
  {
    const int r = tid >> 7;               // row 0..7
    const int h = (tid >> 6) & 1;         // 64-bit word half
    const int j1 = h * 64 + lane;
    const int rowOff = (n * Hh + k0 + r) * Ww;
    const int t1 = tgt[rowOff + j1];
    const int t2 = tgt[rowOff + j1 + 128];
#pragma unroll
    for (int c = 0; c < Cc; ++c) {
      const unsigned long long m1 = __ballot(t1 == c);
      const unsigned long long m2 = __ballot(t2 == c);
      if (lane == 0) {
        smp[r][c][1 + h] = m1;
        smp[r][c][3 + h] = m2;
      }
    }
  }
  __syncthreads();

  const int r = tid >> 7;                 // row 0..7
  const int jj = tid & 127;
  const int rowOut = (n * Hh + k0 + r) * Ww;
#pragma unroll
  for (int half = 0; half < 2; ++half) {
    const int j = jj + half * 128;
    const int S = j + 32;                 // padded bitspace: orig bit x = 64+x
    const int word = S >> 6;              // 0..4
    const int sh = S & 63;
    int d[4];
#pragma unroll
    for (int c = 0; c < Cc; ++c) {
      const unsigned long long* M = smp[r][c];
      const unsigned long long lo = M[word];
      const unsigned long long hi = M[word + 1];
      const unsigned long long win =
          sh ? ((lo >> sh) | (hi << (64 - sh))) : lo;  // bits [j-32, j+31]
      const unsigned long long ml = win & 0x1FFFFFFFFull;  // <= pixel (bit 32)
      const unsigned long long mr = win >> 32;             // >= pixel
      int dd;
      if (ml | mr) {
        const int dl = ml ? (__builtin_clzll(ml) - 31) : 512;
        const int dr = mr ? (int)__builtin_ctzll(mr) : 512;
        dd = min(dl, dr);
      } else {
        // exact rare fallback: full 4-word scan both directions
        int dl = 512, dr = 512;
#pragma unroll
        for (int w = 3; w >= 0; --w) {
          if (w * 64 <= j) {
            unsigned long long m = M[1 + w];
            if (w == (j >> 6)) {
              const int r6 = j & 63;
              m &= (r6 == 63) ? ~0ull : ((1ull << (r6 + 1)) - 1ull);
            }
            if (m && dl == 512) dl = j - (w * 64 + 63 - __builtin_clzll(m));
          }
        }
#pragma unroll
        for (int w = 0; w < 4; ++w) {
          if (w * 64 + 63 >= j) {
            unsigned long long m = M[1 + w];
            if (w == (j >> 6)) m &= ~((1ull << (j & 63)) - 1ull);
            if (m && dr == 512) dr = w * 64 + (int)__builtin_ctzll(m) - j;
          }
        }
        dd = min(min(dl, dr), 512);
      }
      d[c] = dd;
    }
    ushort4 out;
    out.x = (unsigned short)d[0];
    out.y = (unsigned short)d[1];
    out.z = (unsigned short)d[2];
    out.w = (unsigned short)d[3];
    g[rowOut + j] = out;                  // coalesced: lanes = consecutive j
  }
}

// ---------------------------------------------------------------------------
// Kernel B (fused): tile 32i x 64j per block. Register-blocked column pass
// (each thread: one column j, 4 consecutive i, 20 g-row loads straight from
// L2, exact >81 full-column fallback) + in-register softmax from natural-
// layout logits + loss + block reduction + last-block final reduction.
// ---------------------------------------------------------------------------
__global__ __launch_bounds__(512) void fused_kernel(
    const float* __restrict__ in, const ushort4* __restrict__ g,
    float* __restrict__ partials, unsigned* __restrict__ counter,
    float* __restrict__ out) {
  __shared__ float s_w[8];
  __shared__ int s_flag;
  __shared__ float s_red[256];
  const int bid = blockIdx.x;   // 8n * 8 i-tiles * 4 j-tiles = 256
  const int n = bid >> 5;
  const int it = (bid >> 2) & 7;
  const int jt = bid & 3;
  const int tid = threadIdx.x;
  const int jj = tid & 63;
  const int j = jt * 64 + jj;
  const int wq = tid >> 6;                // 0..7, wave-uniform
  const int ibase = it * 32 + wq * 4;     // 4 consecutive i per thread

  const ushort4* gp = g + n * (Hh * Ww) + j;  // + k*Ww

  float d2[4][4];                         // [m][class]
#pragma unroll
  for (int m = 0; m < 4; ++m)
#pragma unroll
    for (int c = 0; c < 4; ++c) d2[m][c] = 3.4e38f;

#pragma unroll
  for (int kq = 0; kq < 20; ++kq) {
    int k = ibase - 8 + kq;
    k = (k < 0) ? 0 : ((k > Hh - 1) ? (Hh - 1) : k);  // dominated dup: safe
    const ushort4 gv = gp[k * Ww];        // coalesced 512B wave load, L2-hot
    const float f0 = (float)((int)gv.x * (int)gv.x);
    const float f1 = (float)((int)gv.y * (int)gv.y);
    const float f2 = (float)((int)gv.z * (int)gv.z);
    const float f3 = (float)((int)gv.w * (int)gv.w);
#pragma unroll
    for (int m = 0; m < 4; ++m) {
      const int diff = m + 8 - kq;        // compile-time constant
      if (diff >= -8 && diff <= 8) {
        const float dd = (float)(diff * diff);
        d2[m][0] = fminf(d2[m][0], f0 + dd);
        d2[m][1] = fminf(d2[m][1], f1 + dd);
        d2[m][2] = fminf(d2[m][2], f2 + dd);
        d2[m][3] = fminf(d2[m][3], f3 + dd);
      }
    }
  }

  float contrib = 0.0f;
  const long cs = (long)Hh * Ww;          // class stride in floats
#pragma unroll
  for (int m = 0; m < 4; ++m) {
    const int i = ibase + m;
    // Exactness: excluded k have (i-k)^2 >= 81; if min <= 81 window is exact.
    const float worst = fmaxf(fmaxf(d2[m][0], d2[m][1]),
                              fmaxf(d2[m][2], d2[m][3]));
    if (worst > 81.0f) {                  // rare exact fallback
      for (int k = 0; k < Hh; ++k) {
        const ushort4 gv = gp[k * Ww];
        const float di = (float)(i - k);
        const float dd = di * di;
        d2[m][0] = fminf(d2[m][0], (float)((int)gv.x * (int)gv.x) + dd);
        d2[m][1] = fminf(d2[m][1], (float)((int)gv.y * (int)gv.y) + dd);
        d2[m][2] = fminf(d2[m][2], (float)((int)gv.z * (int)gv.z) + dd);
        d2[m][3] = fminf(d2[m][3], (float)((int)gv.w * (int)gv.w) + dd);
      }
    }
    const float* lp = in + ((long)(n * Cc) * Hh + i) * Ww + j;
    const float x0 = lp[0];
    const float x1 = lp[cs];
    const float x2 = lp[2 * cs];
    const float x3 = lp[3 * cs];
    const float mx = fmaxf(fmaxf(x0, x1), fmaxf(x2, x3));
    const float e0 = expf(x0 - mx), e1 = expf(x1 - mx);
    const float e2 = expf(x2 - mx), e3 = expf(x3 - mx);
    const float rs = 1.0f / (e0 + e1 + e2 + e3);
    const float p0 = e0 * rs, p1 = e1 * rs, p2 = e2 * rs, p3 = e3 * rs;
    // own-class d2 is exactly 0; exclude it for dbar
    const float q0 = (d2[m][0] == 0.0f) ? 3.4e38f : d2[m][0];
    const float q1 = (d2[m][1] == 0.0f) ? 3.4e38f : d2[m][1];
    const float q2 = (d2[m][2] == 0.0f) ? 3.4e38f : d2[m][2];
    const float q3 = (d2[m][3] == 0.0f) ? 3.4e38f : d2[m][3];
    const float dbar = fminf(fminf(q0, q1), fminf(q2, q3));
    const float pt = (d2[m][0] == 0.0f) ? p0
                   : (d2[m][1] == 0.0f) ? p1
                   : (d2[m][2] == 0.0f) ? p2 : p3;
    contrib += pt * sqrtf(dbar) -
               (p0 * sqrtf(d2[m][0]) + p1 * sqrtf(d2[m][1]) +
                p2 * sqrtf(d2[m][2]) + p3 * sqrtf(d2[m][3]));
  }

  // block reduction (deterministic fixed order)
#pragma unroll
  for (int off = 32; off > 0; off >>= 1) contrib += __shfl_down(contrib, off);
  if ((tid & 63) == 0) s_w[tid >> 6] = contrib;
  __syncthreads();
  if (tid == 0) {
    float v = 0.0f;
#pragma unroll
    for (int w = 0; w < 8; ++w) v += s_w[w];
    partials[bid] = v;
    __threadfence();                      // device-scope: publish partial
    const unsigned t = atomicAdd(counter, 1u);
    s_flag = (t == (unsigned)(gridDim.x - 1));
  }
  __syncthreads();
  if (s_flag) {                           // last block: final reduction
    float v = 0.0f;
    if (tid < 256) v = atomicAdd(&partials[tid], 0.0f);  // coherent read
    if (tid < 256) s_red[tid] = v;
    __syncthreads();
    for (int st = 128; st > 0; st >>= 1) {
      if (tid < st) s_red[tid] += s_red[tid + st];
      __syncthreads();
    }
    if (tid == 0)
      out[0] = s_red[0] / (float)(Cc * Nn) / (65536.0f + 1e-6f);
  }
}

extern "C" void kernel_launch(void* const* d_in, const int* in_sizes, int n_in,
                              void* d_out, int out_size, void* d_ws, size_t ws_size,
                              hipStream_t stream) {
  const float* input = (const float*)d_in[0];   // [8,4,256,256] fp32 logits
  const int* target = (const int*)d_in[1];      // [8,256,256] int32
  float* out = (float*)d_out;                   // scalar fp32
  char* ws = (char*)d_ws;
  ushort4* g = (ushort4*)(ws + OFF_G);
  float* partials = (float*)(ws + OFF_PART);
  unsigned* counter = (unsigned*)(ws + OFF_CNT);

  edt_rows_kernel<<<dim3((Nn * Hh) / 8), dim3(1024), 0, stream>>>(target, g,
                                                                  counter);
  fused_kernel<<<dim3(256), dim3(512), 0, stream>>>(input, g, partials,
                                                    counter, out);
}